// Round 1
// baseline (590.961 us; speedup 1.0000x reference)
//
#include <hip/hip_runtime.h>

// ---------- types ----------
typedef float f32x4 __attribute__((ext_vector_type(4)));
typedef short bh8   __attribute__((ext_vector_type(8)));   // 8 bf16 in 4 VGPRs

#define MFMA16(a, b, c) __builtin_amdgcn_mfma_f32_16x16x32_bf16(a, b, c, 0, 0, 0)

// dims
#define BB 2
#define SS 2048
#define DD 1024
#define HH 16
#define HDIM 64
#define TT (BB * SS)   // 4096

__device__ __forceinline__ unsigned short f2bf(float f) {
  unsigned u = __float_as_uint(f);
  u += 0x7fffu + ((u >> 16) & 1u);   // RNE
  return (unsigned short)(u >> 16);
}

// ---------- fp32 -> bf16 convert (8 elems/thread) ----------
__global__ void cvt_f32_bf16(const float* __restrict__ src,
                             unsigned short* __restrict__ dst, int n8) {
  int i = blockIdx.x * blockDim.x + threadIdx.x;
  if (i >= n8) return;
  const float4* s = (const float4*)src;
  float4 a = s[i * 2 + 0];
  float4 b = s[i * 2 + 1];
  bh8 v;
  v[0] = (short)f2bf(a.x); v[1] = (short)f2bf(a.y);
  v[2] = (short)f2bf(a.z); v[3] = (short)f2bf(a.w);
  v[4] = (short)f2bf(b.x); v[5] = (short)f2bf(b.y);
  v[6] = (short)f2bf(b.z); v[7] = (short)f2bf(b.w);
  *(bh8*)(dst + (size_t)i * 8) = v;
}

// ---------- fused QKV projection: y = x @ W^T + b ----------
// grid (T/64, D/16, 3); block 256 (4 waves, each a 16x16 tile stacked in t)
// z=0 -> Q [B,H,S,Hd], z=1 -> K [B,H,S,Hd], z=2 -> V transposed [B,H,Hd,S]
__global__ __launch_bounds__(256) void qkv_proj(
    const unsigned short* __restrict__ xb,
    const unsigned short* __restrict__ Wqb,
    const unsigned short* __restrict__ Wkb,
    const unsigned short* __restrict__ Wvb,
    const float* __restrict__ bq, const float* __restrict__ bk,
    const float* __restrict__ bv,
    unsigned short* __restrict__ Qw, unsigned short* __restrict__ Kw,
    unsigned short* __restrict__ Vtw) {
  const int lane = threadIdx.x & 63, wid = threadIdx.x >> 6;
  const int c = lane & 15, g = lane >> 4;
  const int t0 = blockIdx.x * 64 + wid * 16;
  const int o0 = blockIdx.y * 16;
  const int z = blockIdx.z;
  const unsigned short* W = (z == 0) ? Wqb : ((z == 1) ? Wkb : Wvb);
  const float* bias = (z == 0) ? bq : ((z == 1) ? bk : bv);

  const unsigned short* arow = xb + (size_t)(t0 + c) * DD + g * 8;
  const unsigned short* brow = W + (size_t)(o0 + c) * DD + g * 8;
  f32x4 acc = {0.f, 0.f, 0.f, 0.f};
#pragma unroll 8
  for (int k = 0; k < DD; k += 32) {
    bh8 af = *(const bh8*)(arow + k);
    bh8 bf = *(const bh8*)(brow + k);
    acc = MFMA16(af, bf, acc);
  }
  const int o = o0 + c;
  const float bia = bias[o];
  const int h = o >> 6, hd = o & 63;
#pragma unroll
  for (int j = 0; j < 4; ++j) {
    int t = t0 + g * 4 + j;
    int b = t >> 11, s = t & (SS - 1);
    unsigned short val = f2bf(acc[j] + bia);
    if (z == 2) {
      Vtw[(((size_t)(b * HH + h) * HDIM + hd) << 11) + s] = val;
    } else {
      unsigned short* O = (z == 0) ? Qw : Kw;
      O[(((size_t)(b * HH + h) * SS + s) << 6) + hd] = val;
    }
  }
}

// ---------- flash attention ----------
// grid (S/64, H, B); block 256 = 4 waves, each owns 16 q-rows. KBLK=64.
__global__ __launch_bounds__(256) void attn_kernel(
    const unsigned short* __restrict__ Qw, const unsigned short* __restrict__ Kw,
    const unsigned short* __restrict__ Vtw, unsigned short* __restrict__ attnw) {
  __shared__ __attribute__((aligned(16))) unsigned short Kt[64][72];
  __shared__ __attribute__((aligned(16))) unsigned short Vt[64][72];
  __shared__ __attribute__((aligned(16))) unsigned short Pt[4][16][72];

  const int tid = threadIdx.x;
  const int lane = tid & 63, wid = tid >> 6;
  const int c = lane & 15, g = lane >> 4;
  const int bh = blockIdx.z * HH + blockIdx.y;
  const unsigned short* Qb = Qw + (size_t)bh * SS * HDIM;
  const unsigned short* Kb = Kw + (size_t)bh * SS * HDIM;
  const unsigned short* Vb = Vtw + (size_t)bh * HDIM * SS;
  const int q0 = blockIdx.x * 64 + wid * 16;

  // Q fragments (hoisted): rows q0+c, hd split in two K=32 chunks
  bh8 qf0 = *(const bh8*)(Qb + (size_t)(q0 + c) * HDIM + g * 8);
  bh8 qf1 = *(const bh8*)(Qb + (size_t)(q0 + c) * HDIM + 32 + g * 8);

  float m[4], l[4];
  f32x4 O[4];
#pragma unroll
  for (int j = 0; j < 4; ++j) {
    m[j] = -1e30f; l[j] = 0.f;
    O[j] = (f32x4){0.f, 0.f, 0.f, 0.f};
  }

  for (int kt = 0; kt < SS / 64; ++kt) {
    const int k0 = kt * 64;
    __syncthreads();   // protect K/V/P from overwrite while prev iter reads
    // stage K tile [64 keys][64 hd] and V^T tile [64 hd][64 keys]
#pragma unroll
    for (int it = 0; it < 2; ++it) {
      int idx = tid + it * 256;
      int row = idx >> 3, ch = (idx & 7) * 8;
      *(bh8*)&Kt[row][ch] = *(const bh8*)(Kb + (size_t)(k0 + row) * HDIM + ch);
      *(bh8*)&Vt[row][ch] = *(const bh8*)(Vb + (size_t)row * SS + k0 + ch);
    }
    __syncthreads();

    // scores: 4 sub-tiles of 16 keys, K-accumulate over hd (2 x K=32)
    f32x4 sc[4];
#pragma unroll
    for (int s4 = 0; s4 < 4; ++s4) {
      f32x4 a = {0.f, 0.f, 0.f, 0.f};
      bh8 kf0 = *(const bh8*)&Kt[s4 * 16 + c][g * 8];
      bh8 kf1 = *(const bh8*)&Kt[s4 * 16 + c][32 + g * 8];
      a = MFMA16(qf0, kf0, a);
      a = MFMA16(qf1, kf1, a);
      sc[s4] = a * 0.125f;   // 1/sqrt(64)
    }
    // row max across 4 sub-tiles + 16 lanes
    float mx[4], al[4], rs[4];
#pragma unroll
    for (int j = 0; j < 4; ++j)
      mx[j] = fmaxf(fmaxf(sc[0][j], sc[1][j]), fmaxf(sc[2][j], sc[3][j]));
#pragma unroll
    for (int msk = 1; msk <= 8; msk <<= 1)
#pragma unroll
      for (int j = 0; j < 4; ++j)
        mx[j] = fmaxf(mx[j], __shfl_xor(mx[j], msk, 16));
#pragma unroll
    for (int j = 0; j < 4; ++j) {
      float mn = fmaxf(m[j], mx[j]);
      al[j] = __expf(m[j] - mn);
      m[j] = mn;
      rs[j] = 0.f;
    }
    // P = exp(sc - m), write transposed via LDS
#pragma unroll
    for (int s4 = 0; s4 < 4; ++s4)
#pragma unroll
      for (int j = 0; j < 4; ++j) {
        float p = __expf(sc[s4][j] - m[j]);
        rs[j] += p;
        Pt[wid][g * 4 + j][s4 * 16 + c] = f2bf(p);
      }
#pragma unroll
    for (int msk = 1; msk <= 8; msk <<= 1)
#pragma unroll
      for (int j = 0; j < 4; ++j)
        rs[j] += __shfl_xor(rs[j], msk, 16);
#pragma unroll
    for (int j = 0; j < 4; ++j) l[j] = l[j] * al[j] + rs[j];
    // rescale O
#pragma unroll
    for (int n = 0; n < 4; ++n)
#pragma unroll
      for (int j = 0; j < 4; ++j) O[n][j] *= al[j];
    __syncthreads();   // P visible to own wave's A-fragment reads (safe)

    // PV: O[16q x 64d] += P[16q x 64k] @ V[64k x 64d]
    bh8 pf0 = *(const bh8*)&Pt[wid][c][g * 8];
    bh8 pf1 = *(const bh8*)&Pt[wid][c][32 + g * 8];
#pragma unroll
    for (int n = 0; n < 4; ++n) {
      bh8 vf0 = *(const bh8*)&Vt[n * 16 + c][g * 8];
      bh8 vf1 = *(const bh8*)&Vt[n * 16 + c][32 + g * 8];
      O[n] = MFMA16(pf0, vf0, O[n]);
      O[n] = MFMA16(pf1, vf1, O[n]);
    }
  }
  // epilogue: attn_out[b*S+s][h*64+d] = O/l  (bf16, [T, D] row-major)
  const int b = blockIdx.z;
  const int col0 = blockIdx.y * 64;
#pragma unroll
  for (int j = 0; j < 4; ++j) {
    float inv = 1.0f / l[j];
    int s = q0 + g * 4 + j;
#pragma unroll
    for (int n = 0; n < 4; ++n) {
      attnw[(size_t)(b * SS + s) * DD + col0 + n * 16 + c] =
          f2bf(O[n][j] * inv);
    }
  }
}

// ---------- output projection: out = attn @ Wo^T + bo (fp32 out) ----------
__global__ __launch_bounds__(256) void out_proj(
    const unsigned short* __restrict__ attnw,
    const unsigned short* __restrict__ Wob, const float* __restrict__ bo,
    float* __restrict__ out) {
  const int lane = threadIdx.x & 63, wid = threadIdx.x >> 6;
  const int c = lane & 15, g = lane >> 4;
  const int t0 = blockIdx.x * 64 + wid * 16;
  const int o0 = blockIdx.y * 16;
  const unsigned short* arow = attnw + (size_t)(t0 + c) * DD + g * 8;
  const unsigned short* brow = Wob + (size_t)(o0 + c) * DD + g * 8;
  f32x4 acc = {0.f, 0.f, 0.f, 0.f};
#pragma unroll 8
  for (int k = 0; k < DD; k += 32) {
    bh8 af = *(const bh8*)(arow + k);
    bh8 bf = *(const bh8*)(brow + k);
    acc = MFMA16(af, bf, acc);
  }
  const int o = o0 + c;
  const float bia = bo[o];
#pragma unroll
  for (int j = 0; j < 4; ++j) {
    int t = t0 + g * 4 + j;
    out[(size_t)t * DD + o] = acc[j] + bia;
  }
}

// ---------- launch ----------
extern "C" void kernel_launch(void* const* d_in, const int* in_sizes, int n_in,
                              void* d_out, int out_size, void* d_ws,
                              size_t ws_size, hipStream_t stream) {
  const float* x  = (const float*)d_in[0];
  const float* Wq = (const float*)d_in[1];
  const float* bq = (const float*)d_in[2];
  const float* Wk = (const float*)d_in[3];
  const float* bk = (const float*)d_in[4];
  const float* Wv = (const float*)d_in[5];
  const float* bv = (const float*)d_in[6];
  const float* Wo = (const float*)d_in[7];
  const float* bo = (const float*)d_in[8];
  float* out = (float*)d_out;

  unsigned short* ws = (unsigned short*)d_ws;
  // ws layout (elements)
  unsigned short* xb   = ws;                    // 4M   x bf16 [T, D]
  unsigned short* Wqb  = ws + 4194304;          // 1M
  unsigned short* Wkb  = ws + 5242880;          // 1M
  unsigned short* Wvb  = ws + 6291456;          // 1M
  unsigned short* Wob  = ws + 7340032;          // 1M
  unsigned short* Qw   = ws + 8388608;          // 4M  [B,H,S,Hd]
  unsigned short* Kw   = ws + 12582912;         // 4M  [B,H,S,Hd]
  unsigned short* Vtw  = ws + 16777216;         // 4M  [B,H,Hd,S]
  unsigned short* attnw= ws + 20971520;         // 4M  [T, D]
  // total 25165824 elems = 48 MB

  // converts
  cvt_f32_bf16<<<(TT * DD / 8 + 255) / 256, 256, 0, stream>>>(x, xb, TT * DD / 8);
  cvt_f32_bf16<<<(DD * DD / 8 + 255) / 256, 256, 0, stream>>>(Wq, Wqb, DD * DD / 8);
  cvt_f32_bf16<<<(DD * DD / 8 + 255) / 256, 256, 0, stream>>>(Wk, Wkb, DD * DD / 8);
  cvt_f32_bf16<<<(DD * DD / 8 + 255) / 256, 256, 0, stream>>>(Wv, Wvb, DD * DD / 8);
  cvt_f32_bf16<<<(DD * DD / 8 + 255) / 256, 256, 0, stream>>>(Wo, Wob, DD * DD / 8);

  // QKV projections
  qkv_proj<<<dim3(TT / 64, DD / 16, 3), 256, 0, stream>>>(
      xb, Wqb, Wkb, Wvb, bq, bk, bv, Qw, Kw, Vtw);

  // flash attention
  attn_kernel<<<dim3(SS / 64, HH, BB), 256, 0, stream>>>(Qw, Kw, Vtw, attnw);

  // output projection
  out_proj<<<dim3(TT / 64, DD / 16), 256, 0, stream>>>(attnw, Wob, bo, out);
}

// Round 2
// 199.889 us; speedup vs baseline: 2.9565x; 2.9565x over previous
//
#include <hip/hip_runtime.h>

// ---------- types ----------
typedef float f32x4 __attribute__((ext_vector_type(4)));
typedef short bh8   __attribute__((ext_vector_type(8)));   // 8 bf16 in 4 VGPRs

#define MFMA16(a, b, c) __builtin_amdgcn_mfma_f32_16x16x32_bf16(a, b, c, 0, 0, 0)

// dims
#define BB 2
#define SS 2048
#define DD 1024
#define HH 16
#define HDIM 64
#define TT (BB * SS)   // 4096

__device__ __forceinline__ unsigned short f2bf(float f) {
  unsigned u = __float_as_uint(f);
  u += 0x7fffu + ((u >> 16) & 1u);   // RNE
  return (unsigned short)(u >> 16);
}

// async global->LDS, 16B per lane. LDS dest must be wave-uniform base;
// HW writes lane l at base + l*16. Global src is per-lane.
__device__ __forceinline__ void gload_lds16(const void* gsrc, const void* ldst) {
  __builtin_amdgcn_global_load_lds(
      (const __attribute__((address_space(1))) unsigned int*)(unsigned long long)gsrc,
      (__attribute__((address_space(3))) unsigned int*)(unsigned int)(unsigned long long)ldst,
      16, 0, 0);
}

// ---------- fp32 -> bf16 convert (8 elems/thread) ----------
__global__ void cvt_f32_bf16(const float* __restrict__ src,
                             unsigned short* __restrict__ dst, int n8) {
  int i = blockIdx.x * blockDim.x + threadIdx.x;
  if (i >= n8) return;
  const float4* s = (const float4*)src;
  float4 a = s[i * 2 + 0];
  float4 b = s[i * 2 + 1];
  bh8 v;
  v[0] = (short)f2bf(a.x); v[1] = (short)f2bf(a.y);
  v[2] = (short)f2bf(a.z); v[3] = (short)f2bf(a.w);
  v[4] = (short)f2bf(b.x); v[5] = (short)f2bf(b.y);
  v[6] = (short)f2bf(b.z); v[7] = (short)f2bf(b.w);
  *(bh8*)(dst + (size_t)i * 8) = v;
}

// ---------- m97-structure GEMM: C[m][n] = sum_k A[m][k]*Bw[n][k] (+bias) ----------
// 128x128 tile, BK=32, 256 thr = 4 waves (2x2), wave = 64x64 = 4x4 frags.
// EPI=0: QKV epilogue (bf16 scatter to Q[B,H,S,Hd], K[B,H,S,Hd], V^T[B,H,Hd,S], N=3072)
// EPI=1: fp32 linear out with bias (N=1024)
template <int EPI>
__global__ __launch_bounds__(256) void gemm128(
    const unsigned short* __restrict__ A,    // [M][1024] bf16
    const unsigned short* __restrict__ Bw,   // [N][1024] bf16 (row-major = W)
    const float* __restrict__ b0, const float* __restrict__ b1,
    const float* __restrict__ b2,
    unsigned short* __restrict__ Qw, unsigned short* __restrict__ Kw,
    unsigned short* __restrict__ Vtw, float* __restrict__ outf) {
  __shared__ __attribute__((aligned(16))) unsigned short As[128 * 32];
  __shared__ __attribute__((aligned(16))) unsigned short Bs[128 * 32];

  const int tid = threadIdx.x, lane = tid & 63, wid = tid >> 6;
  const int c = lane & 15, g = lane >> 4;
  const int wr = wid >> 1, wc = wid & 1;
  const int m0 = blockIdx.x * 128, n0 = blockIdx.y * 128;

  // staging source: row = m0 + rowb + (lane>>2), col = k0 + (lane&3)*8
  const unsigned short* Ab = A + (size_t)(m0 + (lane >> 2)) * DD + (lane & 3) * 8;
  const unsigned short* Bb = Bw + (size_t)(n0 + (lane >> 2)) * DD + (lane & 3) * 8;

  f32x4 acc[4][4];
#pragma unroll
  for (int mi = 0; mi < 4; ++mi)
#pragma unroll
    for (int ni = 0; ni < 4; ++ni) acc[mi][ni] = (f32x4){0.f, 0.f, 0.f, 0.f};

  for (int k0 = 0; k0 < DD; k0 += 32) {
    __syncthreads();   // prev iter's LDS reads complete before overwrite
#pragma unroll
    for (int r = 0; r < 2; ++r) {
      const int rowb = wid * 32 + r * 16;   // wave-uniform 16-row chunk
      gload_lds16(Ab + (size_t)rowb * DD + k0, &As[rowb * 32]);
      gload_lds16(Bb + (size_t)rowb * DD + k0, &Bs[rowb * 32]);
    }
    __syncthreads();   // vmcnt(0) drain: staged tile visible

    bh8 a[4], b[4];
#pragma unroll
    for (int mi = 0; mi < 4; ++mi)
      a[mi] = *(const bh8*)&As[(wr * 64 + mi * 16 + c) * 32 + g * 8];
#pragma unroll
    for (int ni = 0; ni < 4; ++ni)
      b[ni] = *(const bh8*)&Bs[(wc * 64 + ni * 16 + c) * 32 + g * 8];
#pragma unroll
    for (int mi = 0; mi < 4; ++mi)
#pragma unroll
      for (int ni = 0; ni < 4; ++ni)
        acc[mi][ni] = MFMA16(a[mi], b[ni], acc[mi][ni]);
  }

  if (EPI == 0) {
#pragma unroll
    for (int ni = 0; ni < 4; ++ni) {
      const int n = n0 + wc * 64 + ni * 16 + c;   // 0..3071
      const int z = n >> 10, oo = n & 1023;       // z block-uniform
      const float bias = (z == 0 ? b0 : (z == 1 ? b1 : b2))[oo];
      const int h = oo >> 6, hd = oo & 63;
#pragma unroll
      for (int mi = 0; mi < 4; ++mi)
#pragma unroll
        for (int j = 0; j < 4; ++j) {
          const int m = m0 + wr * 64 + mi * 16 + g * 4 + j;
          const int bb = m >> 11, s = m & (SS - 1);
          const unsigned short v = f2bf(acc[mi][ni][j] + bias);
          if (z == 2)
            Vtw[(((size_t)(bb * HH + h) * HDIM + hd) << 11) + s] = v;
          else {
            unsigned short* O = (z == 0) ? Qw : Kw;
            O[(((size_t)(bb * HH + h) * SS + s) << 6) + hd] = v;
          }
        }
    }
  } else {
#pragma unroll
    for (int ni = 0; ni < 4; ++ni) {
      const int n = n0 + wc * 64 + ni * 16 + c;
      const float bias = b0[n];
#pragma unroll
      for (int mi = 0; mi < 4; ++mi)
#pragma unroll
        for (int j = 0; j < 4; ++j) {
          const int m = m0 + wr * 64 + mi * 16 + g * 4 + j;
          outf[(size_t)m * DD + n] = acc[mi][ni][j] + bias;
        }
    }
  }
}

// ---------- flash attention ----------
// grid (S/64, H, B); block 256 = 4 waves, each owns 16 q-rows. KBLK=64.
__global__ __launch_bounds__(256) void attn_kernel(
    const unsigned short* __restrict__ Qw, const unsigned short* __restrict__ Kw,
    const unsigned short* __restrict__ Vtw, unsigned short* __restrict__ attnw) {
  __shared__ __attribute__((aligned(16))) unsigned short Kt[64][72];
  __shared__ __attribute__((aligned(16))) unsigned short Vt[64][72];
  __shared__ __attribute__((aligned(16))) unsigned short Pt[4][16][72];

  const int tid = threadIdx.x;
  const int lane = tid & 63, wid = tid >> 6;
  const int c = lane & 15, g = lane >> 4;
  const int bh = blockIdx.z * HH + blockIdx.y;
  const unsigned short* Qb = Qw + (size_t)bh * SS * HDIM;
  const unsigned short* Kb = Kw + (size_t)bh * SS * HDIM;
  const unsigned short* Vb = Vtw + (size_t)bh * HDIM * SS;
  const int q0 = blockIdx.x * 64 + wid * 16;

  bh8 qf0 = *(const bh8*)(Qb + (size_t)(q0 + c) * HDIM + g * 8);
  bh8 qf1 = *(const bh8*)(Qb + (size_t)(q0 + c) * HDIM + 32 + g * 8);

  float m[4], l[4];
  f32x4 O[4];
#pragma unroll
  for (int j = 0; j < 4; ++j) {
    m[j] = -1e30f; l[j] = 0.f;
    O[j] = (f32x4){0.f, 0.f, 0.f, 0.f};
  }

  for (int kt = 0; kt < SS / 64; ++kt) {
    const int k0 = kt * 64;
    __syncthreads();
#pragma unroll
    for (int it = 0; it < 2; ++it) {
      int idx = tid + it * 256;
      int row = idx >> 3, ch = (idx & 7) * 8;
      *(bh8*)&Kt[row][ch] = *(const bh8*)(Kb + (size_t)(k0 + row) * HDIM + ch);
      *(bh8*)&Vt[row][ch] = *(const bh8*)(Vb + (size_t)row * SS + k0 + ch);
    }
    __syncthreads();

    f32x4 sc[4];
#pragma unroll
    for (int s4 = 0; s4 < 4; ++s4) {
      f32x4 a = {0.f, 0.f, 0.f, 0.f};
      bh8 kf0 = *(const bh8*)&Kt[s4 * 16 + c][g * 8];
      bh8 kf1 = *(const bh8*)&Kt[s4 * 16 + c][32 + g * 8];
      a = MFMA16(qf0, kf0, a);
      a = MFMA16(qf1, kf1, a);
      sc[s4] = a * 0.125f;   // 1/sqrt(64)
    }
    float mx[4], al[4], rs[4];
#pragma unroll
    for (int j = 0; j < 4; ++j)
      mx[j] = fmaxf(fmaxf(sc[0][j], sc[1][j]), fmaxf(sc[2][j], sc[3][j]));
#pragma unroll
    for (int msk = 1; msk <= 8; msk <<= 1)
#pragma unroll
      for (int j = 0; j < 4; ++j)
        mx[j] = fmaxf(mx[j], __shfl_xor(mx[j], msk, 16));
#pragma unroll
    for (int j = 0; j < 4; ++j) {
      float mn = fmaxf(m[j], mx[j]);
      al[j] = __expf(m[j] - mn);
      m[j] = mn;
      rs[j] = 0.f;
    }
#pragma unroll
    for (int s4 = 0; s4 < 4; ++s4)
#pragma unroll
      for (int j = 0; j < 4; ++j) {
        float p = __expf(sc[s4][j] - m[j]);
        rs[j] += p;
        Pt[wid][g * 4 + j][s4 * 16 + c] = f2bf(p);
      }
#pragma unroll
    for (int msk = 1; msk <= 8; msk <<= 1)
#pragma unroll
      for (int j = 0; j < 4; ++j)
        rs[j] += __shfl_xor(rs[j], msk, 16);
#pragma unroll
    for (int j = 0; j < 4; ++j) l[j] = l[j] * al[j] + rs[j];
#pragma unroll
    for (int n = 0; n < 4; ++n)
#pragma unroll
      for (int j = 0; j < 4; ++j) O[n][j] *= al[j];
    __syncthreads();

    bh8 pf0 = *(const bh8*)&Pt[wid][c][g * 8];
    bh8 pf1 = *(const bh8*)&Pt[wid][c][32 + g * 8];
#pragma unroll
    for (int n = 0; n < 4; ++n) {
      bh8 vf0 = *(const bh8*)&Vt[n * 16 + c][g * 8];
      bh8 vf1 = *(const bh8*)&Vt[n * 16 + c][32 + g * 8];
      O[n] = MFMA16(pf0, vf0, O[n]);
      O[n] = MFMA16(pf1, vf1, O[n]);
    }
  }
  const int b = blockIdx.z;
  const int col0 = blockIdx.y * 64;
#pragma unroll
  for (int j = 0; j < 4; ++j) {
    float inv = 1.0f / l[j];
    int s = q0 + g * 4 + j;
#pragma unroll
    for (int n = 0; n < 4; ++n) {
      attnw[(size_t)(b * SS + s) * DD + col0 + n * 16 + c] =
          f2bf(O[n][j] * inv);
    }
  }
}

// ---------- launch ----------
extern "C" void kernel_launch(void* const* d_in, const int* in_sizes, int n_in,
                              void* d_out, int out_size, void* d_ws,
                              size_t ws_size, hipStream_t stream) {
  const float* x  = (const float*)d_in[0];
  const float* Wq = (const float*)d_in[1];
  const float* bq = (const float*)d_in[2];
  const float* Wk = (const float*)d_in[3];
  const float* bk = (const float*)d_in[4];
  const float* Wv = (const float*)d_in[5];
  const float* bv = (const float*)d_in[6];
  const float* Wo = (const float*)d_in[7];
  const float* bo = (const float*)d_in[8];
  float* out = (float*)d_out;

  unsigned short* ws = (unsigned short*)d_ws;
  // ws layout (elements); Wqb/Wkb/Wvb contiguous -> fused [3072][1024] weight
  unsigned short* xb    = ws;                    // 4M  [T, D]
  unsigned short* Wqb   = ws + 4194304;          // 1M
  unsigned short* Wkb   = ws + 5242880;          // 1M
  unsigned short* Wvb   = ws + 6291456;          // 1M
  unsigned short* Wob   = ws + 7340032;          // 1M
  unsigned short* Qw    = ws + 8388608;          // 4M  [B,H,S,Hd]
  unsigned short* Kw    = ws + 12582912;         // 4M  [B,H,S,Hd]
  unsigned short* Vtw   = ws + 16777216;         // 4M  [B,H,Hd,S]
  unsigned short* attnw = ws + 20971520;         // 4M  [T, D]

  cvt_f32_bf16<<<(TT * DD / 8 + 255) / 256, 256, 0, stream>>>(x, xb, TT * DD / 8);
  cvt_f32_bf16<<<(DD * DD / 8 + 255) / 256, 256, 0, stream>>>(Wq, Wqb, DD * DD / 8);
  cvt_f32_bf16<<<(DD * DD / 8 + 255) / 256, 256, 0, stream>>>(Wk, Wkb, DD * DD / 8);
  cvt_f32_bf16<<<(DD * DD / 8 + 255) / 256, 256, 0, stream>>>(Wv, Wvb, DD * DD / 8);
  cvt_f32_bf16<<<(DD * DD / 8 + 255) / 256, 256, 0, stream>>>(Wo, Wob, DD * DD / 8);

  // fused QKV GEMM: M=4096, N=3072, K=1024
  gemm128<0><<<dim3(TT / 128, 3072 / 128), 256, 0, stream>>>(
      xb, Wqb, bq, bk, bv, Qw, Kw, Vtw, nullptr);

  attn_kernel<<<dim3(SS / 64, HH, BB), 256, 0, stream>>>(Qw, Kw, Vtw, attnw);

  // out-proj GEMM: M=4096, N=1024, K=1024
  gemm128<1><<<dim3(TT / 128, DD / 128), 256, 0, stream>>>(
      attnw, Wob, bo, nullptr, nullptr, nullptr, nullptr, nullptr, out);
}

// Round 3
// 141.593 us; speedup vs baseline: 4.1737x; 1.4117x over previous
//
#include <hip/hip_runtime.h>

// ---------- types ----------
typedef float f32x4  __attribute__((ext_vector_type(4)));
typedef float f32x16 __attribute__((ext_vector_type(16)));
typedef short bh8    __attribute__((ext_vector_type(8)));   // 8 bf16 in 4 VGPRs
typedef unsigned int u32;

#define MFMA16(a, b, c) __builtin_amdgcn_mfma_f32_16x16x32_bf16(a, b, c, 0, 0, 0)
#define MFMA32(a, b, c) __builtin_amdgcn_mfma_f32_32x32x16_bf16(a, b, c, 0, 0, 0)

// dims
#define BB 2
#define SS 2048
#define DD 1024
#define HH 16
#define HDIM 64
#define TT (BB * SS)   // 4096

__device__ __forceinline__ unsigned short f2bf(float f) {
  unsigned u = __float_as_uint(f);
  u += 0x7fffu + ((u >> 16) & 1u);   // RNE
  return (unsigned short)(u >> 16);
}
__device__ __forceinline__ u32 pack2(float lo, float hi) {
  return ((u32)f2bf(hi) << 16) | (u32)f2bf(lo);
}

// async global->LDS, 16B per lane (wave-uniform LDS base, lane l -> base+16l)
__device__ __forceinline__ void gload_lds16(const void* gsrc, const void* ldst) {
  __builtin_amdgcn_global_load_lds(
      (const __attribute__((address_space(1))) unsigned int*)(unsigned long long)gsrc,
      (__attribute__((address_space(3))) unsigned int*)(unsigned int)(unsigned long long)ldst,
      16, 0, 0);
}

// ---------- fp32 -> bf16 convert (8 elems/thread) ----------
__global__ void cvt_f32_bf16(const float* __restrict__ src,
                             unsigned short* __restrict__ dst, int n8) {
  int i = blockIdx.x * blockDim.x + threadIdx.x;
  if (i >= n8) return;
  const float4* s = (const float4*)src;
  float4 a = s[i * 2 + 0];
  float4 b = s[i * 2 + 1];
  bh8 v;
  v[0] = (short)f2bf(a.x); v[1] = (short)f2bf(a.y);
  v[2] = (short)f2bf(a.z); v[3] = (short)f2bf(a.w);
  v[4] = (short)f2bf(b.x); v[5] = (short)f2bf(b.y);
  v[6] = (short)f2bf(b.z); v[7] = (short)f2bf(b.w);
  *(bh8*)(dst + (size_t)i * 8) = v;
}

// ---------- m97-structure GEMM (unchanged from R2) ----------
template <int EPI>
__global__ __launch_bounds__(256) void gemm128(
    const unsigned short* __restrict__ A,
    const unsigned short* __restrict__ Bw,
    const float* __restrict__ b0, const float* __restrict__ b1,
    const float* __restrict__ b2,
    unsigned short* __restrict__ Qw, unsigned short* __restrict__ Kw,
    unsigned short* __restrict__ Vtw, float* __restrict__ outf) {
  __shared__ __attribute__((aligned(16))) unsigned short As[128 * 32];
  __shared__ __attribute__((aligned(16))) unsigned short Bs[128 * 32];

  const int tid = threadIdx.x, lane = tid & 63, wid = tid >> 6;
  const int c = lane & 15, g = lane >> 4;
  const int wr = wid >> 1, wc = wid & 1;
  const int m0 = blockIdx.x * 128, n0 = blockIdx.y * 128;

  const unsigned short* Ab = A + (size_t)(m0 + (lane >> 2)) * DD + (lane & 3) * 8;
  const unsigned short* Bb = Bw + (size_t)(n0 + (lane >> 2)) * DD + (lane & 3) * 8;

  f32x4 acc[4][4];
#pragma unroll
  for (int mi = 0; mi < 4; ++mi)
#pragma unroll
    for (int ni = 0; ni < 4; ++ni) acc[mi][ni] = (f32x4){0.f, 0.f, 0.f, 0.f};

  for (int k0 = 0; k0 < DD; k0 += 32) {
    __syncthreads();
#pragma unroll
    for (int r = 0; r < 2; ++r) {
      const int rowb = wid * 32 + r * 16;
      gload_lds16(Ab + (size_t)rowb * DD + k0, &As[rowb * 32]);
      gload_lds16(Bb + (size_t)rowb * DD + k0, &Bs[rowb * 32]);
    }
    __syncthreads();

    bh8 a[4], b[4];
#pragma unroll
    for (int mi = 0; mi < 4; ++mi)
      a[mi] = *(const bh8*)&As[(wr * 64 + mi * 16 + c) * 32 + g * 8];
#pragma unroll
    for (int ni = 0; ni < 4; ++ni)
      b[ni] = *(const bh8*)&Bs[(wc * 64 + ni * 16 + c) * 32 + g * 8];
#pragma unroll
    for (int mi = 0; mi < 4; ++mi)
#pragma unroll
      for (int ni = 0; ni < 4; ++ni)
        acc[mi][ni] = MFMA16(a[mi], b[ni], acc[mi][ni]);
  }

  if (EPI == 0) {
#pragma unroll
    for (int ni = 0; ni < 4; ++ni) {
      const int n = n0 + wc * 64 + ni * 16 + c;
      const int z = n >> 10, oo = n & 1023;
      const float bias = (z == 0 ? b0 : (z == 1 ? b1 : b2))[oo];
      const int h = oo >> 6, hd = oo & 63;
#pragma unroll
      for (int mi = 0; mi < 4; ++mi)
#pragma unroll
        for (int j = 0; j < 4; ++j) {
          const int m = m0 + wr * 64 + mi * 16 + g * 4 + j;
          const int bb = m >> 11, s = m & (SS - 1);
          const unsigned short v = f2bf(acc[mi][ni][j] + bias);
          if (z == 2)
            Vtw[(((size_t)(bb * HH + h) * HDIM + hd) << 11) + s] = v;
          else {
            unsigned short* O = (z == 0) ? Qw : Kw;
            O[(((size_t)(bb * HH + h) * SS + s) << 6) + hd] = v;
          }
        }
    }
  } else {
#pragma unroll
    for (int ni = 0; ni < 4; ++ni) {
      const int n = n0 + wc * 64 + ni * 16 + c;
      const float bias = b0[n];
#pragma unroll
      for (int mi = 0; mi < 4; ++mi)
#pragma unroll
        for (int j = 0; j < 4; ++j) {
          const int m = m0 + wr * 64 + mi * 16 + g * 4 + j;
          outf[(size_t)m * DD + n] = acc[mi][ni][j] + bias;
        }
    }
  }
}

// ---------- flash attention, 8-warp swapped-QK^T (m214 structure) ----------
// grid (S/256, H, B); block 512 = 8 warps, warp owns 32 q-rows. KVBLK=64.
// S^T = mfma32(K,Q): lane (q=l&31, hi=l>>5) holds S[kv][q] for 16 kv per
// 32-kv subtile -> softmax in-register; P redistributed to B-frags via
// pack + shfl_xor(32) + select; PV: O^T[d][q] = mfma32(V^T-frag, P-frag).
__global__ __launch_bounds__(512) void attn2(
    const unsigned short* __restrict__ Qw, const unsigned short* __restrict__ Kw,
    const unsigned short* __restrict__ Vtw, unsigned short* __restrict__ attnw) {
  __shared__ __attribute__((aligned(16))) unsigned short Kt[64][72];
  __shared__ __attribute__((aligned(16))) unsigned short Vt[64][72];

  const int tid = threadIdx.x;
  const int lane = tid & 63, wid = tid >> 6;
  const int q = lane & 31, hi = lane >> 5;
  const int bh = blockIdx.z * HH + blockIdx.y;
  const unsigned short* Qb = Qw + (size_t)bh * SS * HDIM;
  const unsigned short* Kb = Kw + (size_t)bh * SS * HDIM;
  const unsigned short* Vb = Vtw + (size_t)bh * HDIM * SS;
  const int q0 = blockIdx.x * 256 + wid * 32;

  // Q fragments (B-operand): lane (q,hi) holds Q[q0+q][ks*16+8hi .. +7]
  bh8 qf[4];
#pragma unroll
  for (int ks = 0; ks < 4; ++ks)
    qf[ks] = *(const bh8*)(Qb + (size_t)(q0 + q) * HDIM + ks * 16 + hi * 8);

  f32x16 O0, O1;
#pragma unroll
  for (int r = 0; r < 16; ++r) { O0[r] = 0.f; O1[r] = 0.f; }
  float m = -1e30f, l = 0.f;

  // staging: thread t covers row t>>3, 16B chunk (t&7)*8
  const int srow = tid >> 3, scol = (tid & 7) * 8;
  const unsigned short* Ksrc = Kb + (size_t)srow * HDIM + scol;  // +kt*64*64
  const unsigned short* Vsrc = Vb + (size_t)srow * SS + scol;    // +kt*64
  bh8 kreg = *(const bh8*)Ksrc;
  bh8 vreg = *(const bh8*)Vsrc;

  for (int kt = 0; kt < SS / 64; ++kt) {
    __syncthreads();   // all reads of prev tile done
    *(bh8*)&Kt[srow][scol] = kreg;
    *(bh8*)&Vt[srow][scol] = vreg;
    __syncthreads();   // tile visible
    if (kt + 1 < SS / 64) {   // prefetch next tile into regs (T14-lite)
      kreg = *(const bh8*)(Ksrc + (size_t)(kt + 1) * 64 * HDIM);
      vreg = *(const bh8*)(Vsrc + (size_t)(kt + 1) * 64);
    }

#pragma unroll
    for (int kvt = 0; kvt < 2; ++kvt) {
      // QK^T: S^T[32kv][32q], k=Hd via 4 mfma(k=16)
      bh8 kf[4];
#pragma unroll
      for (int ks = 0; ks < 4; ++ks)
        kf[ks] = *(const bh8*)&Kt[kvt * 32 + q][ks * 16 + hi * 8];
      f32x16 acc;
#pragma unroll
      for (int r = 0; r < 16; ++r) acc[r] = 0.f;
#pragma unroll
      for (int ks = 0; ks < 4; ++ks) acc = MFMA32(kf[ks], qf[ks], acc);

      float sc[16];
#pragma unroll
      for (int r = 0; r < 16; ++r) sc[r] = acc[r] * 0.125f;  // 1/sqrt(64)

      // row max: in-lane 16 + cross-hi swap
      float mx = sc[0];
#pragma unroll
      for (int r = 1; r < 16; ++r) mx = fmaxf(mx, sc[r]);
      mx = fmaxf(mx, __shfl_xor(mx, 32));

      // defer-max (T13): only rescale when max grew past THR=8
      if (__any(mx > m + 8.0f)) {
        float mn = fmaxf(m, mx);
        float s2 = __expf(m - mn);
        l *= s2;
#pragma unroll
        for (int r = 0; r < 16; ++r) { O0[r] *= s2; O1[r] *= s2; }
        m = mn;
      }

      float p[16], rs = 0.f;
#pragma unroll
      for (int r = 0; r < 16; ++r) {
        p[r] = __expf(sc[r] - m);
        rs += p[r];
      }
      rs += __shfl_xor(rs, 32);
      l += rs;

      // pack P (reg r -> kv_local=(r&3)+8*(r>>2)+4hi) into B-frag words:
      // B-frag word w at lane(q,hi) must hold kv = slice*16 + 8hi + 2w,2w+1
      u32 w[8];
#pragma unroll
      for (int i = 0; i < 8; ++i) w[i] = pack2(p[2 * i], p[2 * i + 1]);
#pragma unroll
      for (int sl = 0; sl < 2; ++sl) {
        u32 x0 = w[sl * 4 + 0], x1 = w[sl * 4 + 1];
        u32 y0 = w[sl * 4 + 2], y1 = w[sl * 4 + 3];
        u32 x0s = __shfl_xor(x0, 32), x1s = __shfl_xor(x1, 32);
        u32 y0s = __shfl_xor(y0, 32), y1s = __shfl_xor(y1, 32);
        union { u32 uw[4]; bh8 h; } pa;
        pa.uw[0] = hi ? y0s : x0;
        pa.uw[1] = hi ? y1s : x1;
        pa.uw[2] = hi ? y0 : x0s;
        pa.uw[3] = hi ? y1 : x1s;
        // V^T A-frags: lane (d=dt*32+q, hi): V^T[d][kvt*32+sl*16+8hi ..]
        bh8 vf0 = *(const bh8*)&Vt[q][kvt * 32 + sl * 16 + hi * 8];
        bh8 vf1 = *(const bh8*)&Vt[32 + q][kvt * 32 + sl * 16 + hi * 8];
        O0 = MFMA32(vf0, pa.h, O0);
        O1 = MFMA32(vf1, pa.h, O1);
      }
    }
  }

  // epilogue: O^T[d][q]/l -> attnw[(b*S + q0+q)][h*64 + d]
  const float inv = 1.0f / l;
  unsigned short* orow =
      attnw + (size_t)(blockIdx.z * SS + q0 + q) * DD + blockIdx.y * HDIM;
#pragma unroll
  for (int rq = 0; rq < 4; ++rq) {
    const int db0 = 8 * rq + 4 * hi;
    uint2 v0, v1;
    v0.x = pack2(O0[4 * rq + 0] * inv, O0[4 * rq + 1] * inv);
    v0.y = pack2(O0[4 * rq + 2] * inv, O0[4 * rq + 3] * inv);
    v1.x = pack2(O1[4 * rq + 0] * inv, O1[4 * rq + 1] * inv);
    v1.y = pack2(O1[4 * rq + 2] * inv, O1[4 * rq + 3] * inv);
    *(uint2*)(orow + db0) = v0;
    *(uint2*)(orow + 32 + db0) = v1;
  }
}

// ---------- launch ----------
extern "C" void kernel_launch(void* const* d_in, const int* in_sizes, int n_in,
                              void* d_out, int out_size, void* d_ws,
                              size_t ws_size, hipStream_t stream) {
  const float* x  = (const float*)d_in[0];
  const float* Wq = (const float*)d_in[1];
  const float* bq = (const float*)d_in[2];
  const float* Wk = (const float*)d_in[3];
  const float* bk = (const float*)d_in[4];
  const float* Wv = (const float*)d_in[5];
  const float* bv = (const float*)d_in[6];
  const float* Wo = (const float*)d_in[7];
  const float* bo = (const float*)d_in[8];
  float* out = (float*)d_out;

  unsigned short* ws = (unsigned short*)d_ws;
  unsigned short* xb    = ws;                    // 4M  [T, D]
  unsigned short* Wqb   = ws + 4194304;          // 1M
  unsigned short* Wkb   = ws + 5242880;          // 1M
  unsigned short* Wvb   = ws + 6291456;          // 1M
  unsigned short* Wob   = ws + 7340032;          // 1M
  unsigned short* Qw    = ws + 8388608;          // 4M  [B,H,S,Hd]
  unsigned short* Kw    = ws + 12582912;         // 4M  [B,H,S,Hd]
  unsigned short* Vtw   = ws + 16777216;         // 4M  [B,H,Hd,S]
  unsigned short* attnw = ws + 20971520;         // 4M  [T, D]

  cvt_f32_bf16<<<(TT * DD / 8 + 255) / 256, 256, 0, stream>>>(x, xb, TT * DD / 8);
  cvt_f32_bf16<<<(DD * DD / 8 + 255) / 256, 256, 0, stream>>>(Wq, Wqb, DD * DD / 8);
  cvt_f32_bf16<<<(DD * DD / 8 + 255) / 256, 256, 0, stream>>>(Wk, Wkb, DD * DD / 8);
  cvt_f32_bf16<<<(DD * DD / 8 + 255) / 256, 256, 0, stream>>>(Wv, Wvb, DD * DD / 8);
  cvt_f32_bf16<<<(DD * DD / 8 + 255) / 256, 256, 0, stream>>>(Wo, Wob, DD * DD / 8);

  gemm128<0><<<dim3(TT / 128, 3072 / 128), 256, 0, stream>>>(
      xb, Wqb, bq, bk, bv, Qw, Kw, Vtw, nullptr);

  attn2<<<dim3(SS / 256, HH, BB), 512, 0, stream>>>(Qw, Kw, Vtw, attnw);

  gemm128<1><<<dim3(TT / 128, DD / 128), 256, 0, stream>>>(
      attnw, Wob, bo, nullptr, nullptr, nullptr, nullptr, nullptr, out);
}

// Round 4
// 130.144 us; speedup vs baseline: 4.5408x; 1.0880x over previous
//
#include <hip/hip_runtime.h>

// ---------- types ----------
typedef float f32x4  __attribute__((ext_vector_type(4)));
typedef float f32x16 __attribute__((ext_vector_type(16)));
typedef short bh8    __attribute__((ext_vector_type(8)));   // 8 bf16 in 4 VGPRs
typedef unsigned int u32;

#define MFMA16(a, b, c) __builtin_amdgcn_mfma_f32_16x16x32_bf16(a, b, c, 0, 0, 0)
#define MFMA32(a, b, c) __builtin_amdgcn_mfma_f32_32x32x16_bf16(a, b, c, 0, 0, 0)

// dims
#define BB 2
#define SS 2048
#define DD 1024
#define HH 16
#define HDIM 64
#define TT (BB * SS)   // 4096

__device__ __forceinline__ unsigned short f2bf(float f) {
  unsigned u = __float_as_uint(f);
  u += 0x7fffu + ((u >> 16) & 1u);   // RNE
  return (unsigned short)(u >> 16);
}
__device__ __forceinline__ u32 cvtpk(float lo, float hi) {
  u32 r;
  asm("v_cvt_pk_bf16_f32 %0, %1, %2" : "=v"(r) : "v"(lo), "v"(hi));
  return r;
}

// async global->LDS, 16B per lane (wave-uniform LDS base, lane l -> base+16l)
__device__ __forceinline__ void gload_lds16(const void* gsrc, const void* ldst) {
  __builtin_amdgcn_global_load_lds(
      (const __attribute__((address_space(1))) unsigned int*)(unsigned long long)gsrc,
      (__attribute__((address_space(3))) unsigned int*)(unsigned int)(unsigned long long)ldst,
      16, 0, 0);
}

// ---------- fp32 -> bf16 converts ----------
__global__ void cvt_f32_bf16(const float* __restrict__ src,
                             unsigned short* __restrict__ dst, int n8) {
  int i = blockIdx.x * blockDim.x + threadIdx.x;
  if (i >= n8) return;
  const float4* s = (const float4*)src;
  float4 a = s[i * 2 + 0];
  float4 b = s[i * 2 + 1];
  bh8 v;
  v[0] = (short)f2bf(a.x); v[1] = (short)f2bf(a.y);
  v[2] = (short)f2bf(a.z); v[3] = (short)f2bf(a.w);
  v[4] = (short)f2bf(b.x); v[5] = (short)f2bf(b.y);
  v[6] = (short)f2bf(b.z); v[7] = (short)f2bf(b.w);
  *(bh8*)(dst + (size_t)i * 8) = v;
}

// all 4 weight matrices in one launch; dst blocks contiguous (1M elems each)
__global__ void cvt_w4(const float* __restrict__ w0, const float* __restrict__ w1,
                       const float* __restrict__ w2, const float* __restrict__ w3,
                       unsigned short* __restrict__ dst) {
  const int z = blockIdx.y;
  const float* src = (z == 0) ? w0 : (z == 1) ? w1 : (z == 2) ? w2 : w3;
  int i = blockIdx.x * blockDim.x + threadIdx.x;   // 0 .. 131071
  const float4* s = (const float4*)src;
  float4 a = s[i * 2 + 0];
  float4 b = s[i * 2 + 1];
  bh8 v;
  v[0] = (short)f2bf(a.x); v[1] = (short)f2bf(a.y);
  v[2] = (short)f2bf(a.z); v[3] = (short)f2bf(a.w);
  v[4] = (short)f2bf(b.x); v[5] = (short)f2bf(b.y);
  v[6] = (short)f2bf(b.z); v[7] = (short)f2bf(b.w);
  *(bh8*)(dst + (size_t)z * 1048576 + (size_t)i * 8) = v;
}

// ---------- m97-structure GEMM (unchanged from R3) ----------
template <int EPI>
__global__ __launch_bounds__(256) void gemm128(
    const unsigned short* __restrict__ A,
    const unsigned short* __restrict__ Bw,
    const float* __restrict__ b0, const float* __restrict__ b1,
    const float* __restrict__ b2,
    unsigned short* __restrict__ Qw, unsigned short* __restrict__ Kw,
    unsigned short* __restrict__ Vtw, float* __restrict__ outf) {
  __shared__ __attribute__((aligned(16))) unsigned short As[128 * 32];
  __shared__ __attribute__((aligned(16))) unsigned short Bs[128 * 32];

  const int tid = threadIdx.x, lane = tid & 63, wid = tid >> 6;
  const int c = lane & 15, g = lane >> 4;
  const int wr = wid >> 1, wc = wid & 1;
  const int m0 = blockIdx.x * 128, n0 = blockIdx.y * 128;

  const unsigned short* Ab = A + (size_t)(m0 + (lane >> 2)) * DD + (lane & 3) * 8;
  const unsigned short* Bb = Bw + (size_t)(n0 + (lane >> 2)) * DD + (lane & 3) * 8;

  f32x4 acc[4][4];
#pragma unroll
  for (int mi = 0; mi < 4; ++mi)
#pragma unroll
    for (int ni = 0; ni < 4; ++ni) acc[mi][ni] = (f32x4){0.f, 0.f, 0.f, 0.f};

  for (int k0 = 0; k0 < DD; k0 += 32) {
    __syncthreads();
#pragma unroll
    for (int r = 0; r < 2; ++r) {
      const int rowb = wid * 32 + r * 16;
      gload_lds16(Ab + (size_t)rowb * DD + k0, &As[rowb * 32]);
      gload_lds16(Bb + (size_t)rowb * DD + k0, &Bs[rowb * 32]);
    }
    __syncthreads();

    bh8 a[4], b[4];
#pragma unroll
    for (int mi = 0; mi < 4; ++mi)
      a[mi] = *(const bh8*)&As[(wr * 64 + mi * 16 + c) * 32 + g * 8];
#pragma unroll
    for (int ni = 0; ni < 4; ++ni)
      b[ni] = *(const bh8*)&Bs[(wc * 64 + ni * 16 + c) * 32 + g * 8];
#pragma unroll
    for (int mi = 0; mi < 4; ++mi)
#pragma unroll
      for (int ni = 0; ni < 4; ++ni)
        acc[mi][ni] = MFMA16(a[mi], b[ni], acc[mi][ni]);
  }

  if (EPI == 0) {
#pragma unroll
    for (int ni = 0; ni < 4; ++ni) {
      const int n = n0 + wc * 64 + ni * 16 + c;
      const int z = n >> 10, oo = n & 1023;
      const float bias = (z == 0 ? b0 : (z == 1 ? b1 : b2))[oo];
      const int h = oo >> 6, hd = oo & 63;
#pragma unroll
      for (int mi = 0; mi < 4; ++mi)
#pragma unroll
        for (int j = 0; j < 4; ++j) {
          const int m = m0 + wr * 64 + mi * 16 + g * 4 + j;
          const int bb = m >> 11, s = m & (SS - 1);
          const unsigned short v = f2bf(acc[mi][ni][j] + bias);
          if (z == 2)
            Vtw[(((size_t)(bb * HH + h) * HDIM + hd) << 11) + s] = v;
          else {
            unsigned short* O = (z == 0) ? Qw : Kw;
            O[(((size_t)(bb * HH + h) * SS + s) << 6) + hd] = v;
          }
        }
    }
  } else {
#pragma unroll
    for (int ni = 0; ni < 4; ++ni) {
      const int n = n0 + wc * 64 + ni * 16 + c;
      const float bias = b0[n];
#pragma unroll
      for (int mi = 0; mi < 4; ++mi)
#pragma unroll
        for (int j = 0; j < 4; ++j) {
          const int m = m0 + wr * 64 + mi * 16 + g * 4 + j;
          outf[(size_t)m * DD + n] = acc[mi][ni][j] + bias;
        }
    }
  }
}

// ---------- flash attention, 4-warp swapped-QK^T, double-buffered ----------
// grid: 512 blocks (chunk-swizzled for XCD L2 locality); block 256 = 4 warps,
// warp owns 32 q-rows (QBLK=128). KVBLK=64, 2 LDS buffers, 1 barrier/tile.
__global__ __launch_bounds__(256) void attn3(
    const unsigned short* __restrict__ Qw, const unsigned short* __restrict__ Kw,
    const unsigned short* __restrict__ Vtw, unsigned short* __restrict__ attnw) {
  __shared__ __attribute__((aligned(16))) unsigned short Kt[2][64][72];
  __shared__ __attribute__((aligned(16))) unsigned short Vt[2][64][72];

  // bijective chunked XCD swizzle: flat f -> work (f%8)*64 + f/8  (512 blocks)
  const int f = blockIdx.x;
  const int work = (f & 7) * 64 + (f >> 3);
  const int bx = work & 15;          // q-block: S/128
  const int by = (work >> 4) & 15;   // head
  const int bz = work >> 8;          // batch

  const int tid = threadIdx.x;
  const int lane = tid & 63, wid = tid >> 6;
  const int q = lane & 31, hi = lane >> 5;
  const int bh = bz * HH + by;
  const unsigned short* Qb = Qw + (size_t)bh * SS * HDIM;
  const unsigned short* Kb = Kw + (size_t)bh * SS * HDIM;
  const unsigned short* Vb = Vtw + (size_t)bh * HDIM * SS;
  const int q0 = bx * 128 + wid * 32;

  // Q fragments (B-operand): lane (q,hi) holds Q[q0+q][ks*16+8hi .. +7]
  bh8 qf[4];
#pragma unroll
  for (int ks = 0; ks < 4; ++ks)
    qf[ks] = *(const bh8*)(Qb + (size_t)(q0 + q) * HDIM + ks * 16 + hi * 8);

  f32x16 O0, O1;
#pragma unroll
  for (int r = 0; r < 16; ++r) { O0[r] = 0.f; O1[r] = 0.f; }
  float m = -1e30f, l = 0.f;

  // staging: thread t covers row t>>2, 32B chunk at col (t&3)*16
  const int srow = tid >> 2, scol = (tid & 3) * 16;
  const unsigned short* Ksrc = Kb + (size_t)srow * HDIM + scol;  // +kt*64*64
  const unsigned short* Vsrc = Vb + (size_t)srow * SS + scol;    // +kt*64
  bh8 kr0 = *(const bh8*)(Ksrc + 0), kr1 = *(const bh8*)(Ksrc + 8);
  bh8 vr0 = *(const bh8*)(Vsrc + 0), vr1 = *(const bh8*)(Vsrc + 8);
  // write tile 0 into buf 0 (visible after first barrier)
  *(bh8*)&Kt[0][srow][scol] = kr0; *(bh8*)&Kt[0][srow][scol + 8] = kr1;
  *(bh8*)&Vt[0][srow][scol] = vr0; *(bh8*)&Vt[0][srow][scol + 8] = vr1;
  kr0 = *(const bh8*)(Ksrc + 64 * HDIM); kr1 = *(const bh8*)(Ksrc + 64 * HDIM + 8);
  vr0 = *(const bh8*)(Vsrc + 64);        vr1 = *(const bh8*)(Vsrc + 64 + 8);

  const int NT = SS / 64;
  for (int kt = 0; kt < NT; ++kt) {
    const int cur = kt & 1;
    __syncthreads();   // tile kt visible; all reads of buf cur^1 (tile kt-1) done
    if (kt + 1 < NT) { // write tile kt+1 into other buffer; prefetch kt+2
      *(bh8*)&Kt[cur ^ 1][srow][scol] = kr0;
      *(bh8*)&Kt[cur ^ 1][srow][scol + 8] = kr1;
      *(bh8*)&Vt[cur ^ 1][srow][scol] = vr0;
      *(bh8*)&Vt[cur ^ 1][srow][scol + 8] = vr1;
      if (kt + 2 < NT) {
        const size_t ko = (size_t)(kt + 2) * 64 * HDIM, vo = (size_t)(kt + 2) * 64;
        kr0 = *(const bh8*)(Ksrc + ko); kr1 = *(const bh8*)(Ksrc + ko + 8);
        vr0 = *(const bh8*)(Vsrc + vo); vr1 = *(const bh8*)(Vsrc + vo + 8);
      }
    }

#pragma unroll
    for (int kvt = 0; kvt < 2; ++kvt) {
      // QK^T: S^T[32kv][32q]
      bh8 kf[4];
#pragma unroll
      for (int ks = 0; ks < 4; ++ks)
        kf[ks] = *(const bh8*)&Kt[cur][kvt * 32 + q][ks * 16 + hi * 8];
      f32x16 acc;
#pragma unroll
      for (int r = 0; r < 16; ++r) acc[r] = 0.f;
      __builtin_amdgcn_s_setprio(1);
#pragma unroll
      for (int ks = 0; ks < 4; ++ks) acc = MFMA32(kf[ks], qf[ks], acc);
      __builtin_amdgcn_s_setprio(0);

      float sc[16];
#pragma unroll
      for (int r = 0; r < 16; ++r) sc[r] = acc[r] * 0.125f;  // 1/sqrt(64)

      float mx = sc[0];
#pragma unroll
      for (int r = 1; r < 16; ++r) mx = fmaxf(mx, sc[r]);
      mx = fmaxf(mx, __shfl_xor(mx, 32));

      // defer-max (T13): only rescale when max grew past THR=8
      if (__any(mx > m + 8.0f)) {
        float mn = fmaxf(m, mx);
        float s2 = __expf(m - mn);
        l *= s2;
#pragma unroll
        for (int r = 0; r < 16; ++r) { O0[r] *= s2; O1[r] *= s2; }
        m = mn;
      }

      float p[16], rs = 0.f;
#pragma unroll
      for (int r = 0; r < 16; ++r) {
        p[r] = __expf(sc[r] - m);
        rs += p[r];
      }
      rs += __shfl_xor(rs, 32);
      l += rs;

      // pack P into B-frag words via cvt_pk (T12) + cross-hi shfl exchange
      u32 w[8];
#pragma unroll
      for (int i = 0; i < 8; ++i) w[i] = cvtpk(p[2 * i], p[2 * i + 1]);
#pragma unroll
      for (int sl = 0; sl < 2; ++sl) {
        u32 x0 = w[sl * 4 + 0], x1 = w[sl * 4 + 1];
        u32 y0 = w[sl * 4 + 2], y1 = w[sl * 4 + 3];
        u32 x0s = __shfl_xor(x0, 32), x1s = __shfl_xor(x1, 32);
        u32 y0s = __shfl_xor(y0, 32), y1s = __shfl_xor(y1, 32);
        union { u32 uw[4]; bh8 h; } pa;
        pa.uw[0] = hi ? y0s : x0;
        pa.uw[1] = hi ? y1s : x1;
        pa.uw[2] = hi ? y0 : x0s;
        pa.uw[3] = hi ? y1 : x1s;
        bh8 vf0 = *(const bh8*)&Vt[cur][q][kvt * 32 + sl * 16 + hi * 8];
        bh8 vf1 = *(const bh8*)&Vt[cur][32 + q][kvt * 32 + sl * 16 + hi * 8];
        __builtin_amdgcn_s_setprio(1);
        O0 = MFMA32(vf0, pa.h, O0);
        O1 = MFMA32(vf1, pa.h, O1);
        __builtin_amdgcn_s_setprio(0);
      }
    }
  }

  // epilogue: O^T[d][q]/l -> attnw[(b*S + q0+q)][h*64 + d]
  const float inv = 1.0f / l;
  unsigned short* orow =
      attnw + (size_t)(bz * SS + q0 + q) * DD + by * HDIM;
#pragma unroll
  for (int rq = 0; rq < 4; ++rq) {
    const int db0 = 8 * rq + 4 * hi;
    uint2 v0, v1;
    v0.x = cvtpk(O0[4 * rq + 0] * inv, O0[4 * rq + 1] * inv);
    v0.y = cvtpk(O0[4 * rq + 2] * inv, O0[4 * rq + 3] * inv);
    v1.x = cvtpk(O1[4 * rq + 0] * inv, O1[4 * rq + 1] * inv);
    v1.y = cvtpk(O1[4 * rq + 2] * inv, O1[4 * rq + 3] * inv);
    *(uint2*)(orow + db0) = v0;
    *(uint2*)(orow + 32 + db0) = v1;
  }
}

// ---------- launch ----------
extern "C" void kernel_launch(void* const* d_in, const int* in_sizes, int n_in,
                              void* d_out, int out_size, void* d_ws,
                              size_t ws_size, hipStream_t stream) {
  const float* x  = (const float*)d_in[0];
  const float* Wq = (const float*)d_in[1];
  const float* bq = (const float*)d_in[2];
  const float* Wk = (const float*)d_in[3];
  const float* bk = (const float*)d_in[4];
  const float* Wv = (const float*)d_in[5];
  const float* bv = (const float*)d_in[6];
  const float* Wo = (const float*)d_in[7];
  const float* bo = (const float*)d_in[8];
  float* out = (float*)d_out;

  unsigned short* ws = (unsigned short*)d_ws;
  unsigned short* xb    = ws;                    // 4M  [T, D]
  unsigned short* Wqb   = ws + 4194304;          // 1M (Wq,Wk,Wv,Wo contiguous)
  unsigned short* Qw    = ws + 8388608;          // 4M  [B,H,S,Hd]
  unsigned short* Kw    = ws + 12582912;         // 4M  [B,H,S,Hd]
  unsigned short* Vtw   = ws + 16777216;         // 4M  [B,H,Hd,S]
  unsigned short* attnw = ws + 20971520;         // 4M  [T, D]

  cvt_f32_bf16<<<(TT * DD / 8 + 255) / 256, 256, 0, stream>>>(x, xb, TT * DD / 8);
  cvt_w4<<<dim3(DD * DD / 8 / 256, 4), 256, 0, stream>>>(Wq, Wk, Wv, Wo, Wqb);

  gemm128<0><<<dim3(TT / 128, 3072 / 128), 256, 0, stream>>>(
      xb, Wqb, bq, bk, bv, Qw, Kw, Vtw, nullptr);

  attn3<<<dim3(512), 256, 0, stream>>>(Qw, Kw, Vtw, attnw);

  gemm128<1><<<dim3(TT / 128, DD / 128), 256, 0, stream>>>(
      attnw, Wqb + 3 * 1048576, bo, nullptr, nullptr, nullptr, nullptr, nullptr, out);
}

// Round 6
// 122.745 us; speedup vs baseline: 4.8145x; 1.0603x over previous
//
#include <hip/hip_runtime.h>

// ---------- types ----------
typedef float f32x4  __attribute__((ext_vector_type(4)));
typedef float f32x16 __attribute__((ext_vector_type(16)));
typedef short bh8    __attribute__((ext_vector_type(8)));   // 8 bf16 in 4 VGPRs
typedef unsigned int u32;

#define MFMA16(a, b, c) __builtin_amdgcn_mfma_f32_16x16x32_bf16(a, b, c, 0, 0, 0)
#define MFMA32(a, b, c) __builtin_amdgcn_mfma_f32_32x32x16_bf16(a, b, c, 0, 0, 0)

// dims
#define BB 2
#define SS 2048
#define DD 1024
#define HH 16
#define HDIM 64
#define TT (BB * SS)   // 4096

#define QSCALE 0.18033688011f   // log2(e)/8 : folds 1/sqrt(64) + exp->exp2
#define THR2 11.5f               // defer-max threshold, log2 domain (~8 nats)

__device__ __forceinline__ unsigned short f2bf(float f) {
  unsigned u = __float_as_uint(f);
  u += 0x7fffu + ((u >> 16) & 1u);   // RNE
  return (unsigned short)(u >> 16);
}
__device__ __forceinline__ u32 cvtpk(float lo, float hi) {
  u32 r;
  asm("v_cvt_pk_bf16_f32 %0, %1, %2" : "=v"(r) : "v"(lo), "v"(hi));
  return r;
}
// gfx950 ISA: v_permlane32_swap_b32 vdst, vsrc swaps vdst rows 2,3 (lanes
// 32:63) with vsrc rows 0,1 (lanes 0:31):  a[32:63] <-> b[0:31].
#define PLSWAP(a, b) \
  asm("v_permlane32_swap_b32 %0, %1" : "+v"(a), "+v"(b))

// async global->LDS, 16B per lane (wave-uniform LDS base, lane l -> base+16l)
__device__ __forceinline__ void gload_lds16(const void* gsrc, const void* ldst) {
  __builtin_amdgcn_global_load_lds(
      (const __attribute__((address_space(1))) unsigned int*)(unsigned long long)gsrc,
      (__attribute__((address_space(3))) unsigned int*)(unsigned int)(unsigned long long)ldst,
      16, 0, 0);
}

// ---------- fp32 -> bf16 converts ----------
__global__ void cvt_f32_bf16(const float* __restrict__ src,
                             unsigned short* __restrict__ dst, int n8) {
  int i = blockIdx.x * blockDim.x + threadIdx.x;
  if (i >= n8) return;
  const float4* s = (const float4*)src;
  float4 a = s[i * 2 + 0];
  float4 b = s[i * 2 + 1];
  bh8 v;
  v[0] = (short)f2bf(a.x); v[1] = (short)f2bf(a.y);
  v[2] = (short)f2bf(a.z); v[3] = (short)f2bf(a.w);
  v[4] = (short)f2bf(b.x); v[5] = (short)f2bf(b.y);
  v[6] = (short)f2bf(b.z); v[7] = (short)f2bf(b.w);
  *(bh8*)(dst + (size_t)i * 8) = v;
}

__global__ void cvt_w4(const float* __restrict__ w0, const float* __restrict__ w1,
                       const float* __restrict__ w2, const float* __restrict__ w3,
                       unsigned short* __restrict__ dst) {
  const int z = blockIdx.y;
  const float* src = (z == 0) ? w0 : (z == 1) ? w1 : (z == 2) ? w2 : w3;
  int i = blockIdx.x * blockDim.x + threadIdx.x;   // 0 .. 131071
  const float4* s = (const float4*)src;
  float4 a = s[i * 2 + 0];
  float4 b = s[i * 2 + 1];
  bh8 v;
  v[0] = (short)f2bf(a.x); v[1] = (short)f2bf(a.y);
  v[2] = (short)f2bf(a.z); v[3] = (short)f2bf(a.w);
  v[4] = (short)f2bf(b.x); v[5] = (short)f2bf(b.y);
  v[6] = (short)f2bf(b.z); v[7] = (short)f2bf(b.w);
  *(bh8*)(dst + (size_t)z * 1048576 + (size_t)i * 8) = v;
}

// ---------- m97-structure GEMM ----------
// EPI=0: QKV epilogue; Q is pre-scaled by QSCALE (log2-domain softmax).
template <int EPI>
__global__ __launch_bounds__(256) void gemm128(
    const unsigned short* __restrict__ A,
    const unsigned short* __restrict__ Bw,
    const float* __restrict__ b0, const float* __restrict__ b1,
    const float* __restrict__ b2,
    unsigned short* __restrict__ Qw, unsigned short* __restrict__ Kw,
    unsigned short* __restrict__ Vtw, float* __restrict__ outf) {
  __shared__ __attribute__((aligned(16))) unsigned short As[128 * 32];
  __shared__ __attribute__((aligned(16))) unsigned short Bs[128 * 32];

  const int tid = threadIdx.x, lane = tid & 63, wid = tid >> 6;
  const int c = lane & 15, g = lane >> 4;
  const int wr = wid >> 1, wc = wid & 1;
  const int m0 = blockIdx.x * 128, n0 = blockIdx.y * 128;

  const unsigned short* Ab = A + (size_t)(m0 + (lane >> 2)) * DD + (lane & 3) * 8;
  const unsigned short* Bb = Bw + (size_t)(n0 + (lane >> 2)) * DD + (lane & 3) * 8;

  f32x4 acc[4][4];
#pragma unroll
  for (int mi = 0; mi < 4; ++mi)
#pragma unroll
    for (int ni = 0; ni < 4; ++ni) acc[mi][ni] = (f32x4){0.f, 0.f, 0.f, 0.f};

  for (int k0 = 0; k0 < DD; k0 += 32) {
    __syncthreads();
#pragma unroll
    for (int r = 0; r < 2; ++r) {
      const int rowb = wid * 32 + r * 16;
      gload_lds16(Ab + (size_t)rowb * DD + k0, &As[rowb * 32]);
      gload_lds16(Bb + (size_t)rowb * DD + k0, &Bs[rowb * 32]);
    }
    __syncthreads();

    bh8 a[4], b[4];
#pragma unroll
    for (int mi = 0; mi < 4; ++mi)
      a[mi] = *(const bh8*)&As[(wr * 64 + mi * 16 + c) * 32 + g * 8];
#pragma unroll
    for (int ni = 0; ni < 4; ++ni)
      b[ni] = *(const bh8*)&Bs[(wc * 64 + ni * 16 + c) * 32 + g * 8];
#pragma unroll
    for (int mi = 0; mi < 4; ++mi)
#pragma unroll
      for (int ni = 0; ni < 4; ++ni)
        acc[mi][ni] = MFMA16(a[mi], b[ni], acc[mi][ni]);
  }

  if (EPI == 0) {
#pragma unroll
    for (int ni = 0; ni < 4; ++ni) {
      const int n = n0 + wc * 64 + ni * 16 + c;
      const int z = n >> 10, oo = n & 1023;
      const float bias = (z == 0 ? b0 : (z == 1 ? b1 : b2))[oo];
      const int h = oo >> 6, hd = oo & 63;
#pragma unroll
      for (int mi = 0; mi < 4; ++mi)
#pragma unroll
        for (int j = 0; j < 4; ++j) {
          const int m = m0 + wr * 64 + mi * 16 + g * 4 + j;
          const int bb = m >> 11, s = m & (SS - 1);
          float vv = acc[mi][ni][j] + bias;
          if (z == 0) vv *= QSCALE;   // pre-scale Q for log2-domain softmax
          const unsigned short v = f2bf(vv);
          if (z == 2)
            Vtw[(((size_t)(bb * HH + h) * HDIM + hd) << 11) + s] = v;
          else {
            unsigned short* O = (z == 0) ? Qw : Kw;
            O[(((size_t)(bb * HH + h) * SS + s) << 6) + hd] = v;
          }
        }
    }
  } else {
#pragma unroll
    for (int ni = 0; ni < 4; ++ni) {
      const int n = n0 + wc * 64 + ni * 16 + c;
      const float bias = b0[n];
#pragma unroll
      for (int mi = 0; mi < 4; ++mi)
#pragma unroll
        for (int j = 0; j < 4; ++j) {
          const int m = m0 + wr * 64 + mi * 16 + g * 4 + j;
          outf[(size_t)m * DD + n] = acc[mi][ni][j] + bias;
        }
    }
  }
}

// ---------- flash attention v4: batched-kvt phases, log2 softmax, permlane ----------
// grid 512 (XCD-chunk-swizzled); block 256 = 4 warps x 32 q-rows. KVBLK=64,
// double-buffered LDS, 1 barrier/tile.
__global__ __launch_bounds__(256) void attn4(
    const unsigned short* __restrict__ Qw, const unsigned short* __restrict__ Kw,
    const unsigned short* __restrict__ Vtw, unsigned short* __restrict__ attnw) {
  __shared__ __attribute__((aligned(16))) unsigned short Kt[2][64][72];
  __shared__ __attribute__((aligned(16))) unsigned short Vt[2][64][72];

  // bijective chunked XCD swizzle: flat f -> work (f%8)*64 + f/8  (512 blocks)
  const int f = blockIdx.x;
  const int work = (f & 7) * 64 + (f >> 3);
  const int bx = work & 15;          // q-block: S/128
  const int by = (work >> 4) & 15;   // head
  const int bz = work >> 8;          // batch

  const int tid = threadIdx.x;
  const int lane = tid & 63, wid = tid >> 6;
  const int q = lane & 31, hi = lane >> 5;
  const int bh = bz * HH + by;
  const unsigned short* Qb = Qw + (size_t)bh * SS * HDIM;
  const unsigned short* Kb = Kw + (size_t)bh * SS * HDIM;
  const unsigned short* Vb = Vtw + (size_t)bh * HDIM * SS;
  const int q0 = bx * 128 + wid * 32;

  // Q fragments (pre-scaled by QSCALE at the QKV GEMM epilogue)
  bh8 qf[4];
#pragma unroll
  for (int ks = 0; ks < 4; ++ks)
    qf[ks] = *(const bh8*)(Qb + (size_t)(q0 + q) * HDIM + ks * 16 + hi * 8);

  f32x16 O0, O1;
#pragma unroll
  for (int r = 0; r < 16; ++r) { O0[r] = 0.f; O1[r] = 0.f; }
  float m2 = -1e30f, l = 0.f;

  // staging: thread t covers row t>>2, 32B chunk at col (t&3)*16
  const int srow = tid >> 2, scol = (tid & 3) * 16;
  const unsigned short* Ksrc = Kb + (size_t)srow * HDIM + scol;  // +kt*64*64
  const unsigned short* Vsrc = Vb + (size_t)srow * SS + scol;    // +kt*64
  bh8 kr0 = *(const bh8*)(Ksrc + 0), kr1 = *(const bh8*)(Ksrc + 8);
  bh8 vr0 = *(const bh8*)(Vsrc + 0), vr1 = *(const bh8*)(Vsrc + 8);
  *(bh8*)&Kt[0][srow][scol] = kr0; *(bh8*)&Kt[0][srow][scol + 8] = kr1;
  *(bh8*)&Vt[0][srow][scol] = vr0; *(bh8*)&Vt[0][srow][scol + 8] = vr1;
  kr0 = *(const bh8*)(Ksrc + 64 * HDIM); kr1 = *(const bh8*)(Ksrc + 64 * HDIM + 8);
  vr0 = *(const bh8*)(Vsrc + 64);        vr1 = *(const bh8*)(Vsrc + 64 + 8);

  const int NT = SS / 64;
  for (int kt = 0; kt < NT; ++kt) {
    const int cur = kt & 1;
    __syncthreads();   // tile kt visible; reads of buf cur^1 (tile kt-1) done

    // K fragments for BOTH kvt subtiles (8 ds_read_b128, issued together)
    bh8 kf0[4], kf1[4];
#pragma unroll
    for (int ks = 0; ks < 4; ++ks) {
      kf0[ks] = *(const bh8*)&Kt[cur][q][ks * 16 + hi * 8];
      kf1[ks] = *(const bh8*)&Kt[cur][32 + q][ks * 16 + hi * 8];
    }

    // stage tile kt+1 into other buffer; prefetch kt+2 into regs
    if (kt + 1 < NT) {
      *(bh8*)&Kt[cur ^ 1][srow][scol] = kr0;
      *(bh8*)&Kt[cur ^ 1][srow][scol + 8] = kr1;
      *(bh8*)&Vt[cur ^ 1][srow][scol] = vr0;
      *(bh8*)&Vt[cur ^ 1][srow][scol + 8] = vr1;
      if (kt + 2 < NT) {
        const size_t ko = (size_t)(kt + 2) * 64 * HDIM, vo = (size_t)(kt + 2) * 64;
        kr0 = *(const bh8*)(Ksrc + ko); kr1 = *(const bh8*)(Ksrc + ko + 8);
        vr0 = *(const bh8*)(Vsrc + vo); vr1 = *(const bh8*)(Vsrc + vo + 8);
      }
    }

    // QK^T both subtiles: acc = log2-domain scores (Q pre-scaled)
    f32x16 a0, a1;
#pragma unroll
    for (int r = 0; r < 16; ++r) { a0[r] = 0.f; a1[r] = 0.f; }
    __builtin_amdgcn_s_setprio(1);
#pragma unroll
    for (int ks = 0; ks < 4; ++ks) a0 = MFMA32(kf0[ks], qf[ks], a0);
#pragma unroll
    for (int ks = 0; ks < 4; ++ks) a1 = MFMA32(kf1[ks], qf[ks], a1);
    __builtin_amdgcn_s_setprio(0);

    // V^T A-fragments (issue early; consumed after softmax)
    bh8 vf[2][2][2];   // [kvt][sl][dblk]
#pragma unroll
    for (int kvt = 0; kvt < 2; ++kvt)
#pragma unroll
      for (int sl = 0; sl < 2; ++sl) {
        vf[kvt][sl][0] = *(const bh8*)&Vt[cur][q][kvt * 32 + sl * 16 + hi * 8];
        vf[kvt][sl][1] = *(const bh8*)&Vt[cur][32 + q][kvt * 32 + sl * 16 + hi * 8];
      }

    // ---- softmax over 32 values (log2 domain) ----
    float t8[8];
#pragma unroll
    for (int i = 0; i < 8; ++i)
      t8[i] = fmaxf(fmaxf(a0[2 * i], a0[2 * i + 1]),
                    fmaxf(a1[2 * i], a1[2 * i + 1]));
    float mx = fmaxf(fmaxf(fmaxf(t8[0], t8[1]), fmaxf(t8[2], t8[3])),
                     fmaxf(fmaxf(t8[4], t8[5]), fmaxf(t8[6], t8[7])));
    {
      float xa = mx, xb = mx;
      asm("" : "+v"(xb));          // keep xb a distinct VGPR
      PLSWAP(xa, xb);              // orientation-immune dup-swap reduce
      mx = fmaxf(xa, xb);
    }

    if (__any(mx > m2 + THR2)) {   // defer-max (T13)
      float mn = fmaxf(m2, mx);
      float s2 = __builtin_amdgcn_exp2f(m2 - mn);
      l *= s2;
#pragma unroll
      for (int r = 0; r < 16; ++r) { O0[r] *= s2; O1[r] *= s2; }
      m2 = mn;
    }

    float p0[16], p1[16];
#pragma unroll
    for (int r = 0; r < 16; ++r) {
      p0[r] = __builtin_amdgcn_exp2f(a0[r] - m2);
      p1[r] = __builtin_amdgcn_exp2f(a1[r] - m2);
    }
    float s8[8];
#pragma unroll
    for (int i = 0; i < 8; ++i)
      s8[i] = (p0[2 * i] + p0[2 * i + 1]) + (p1[2 * i] + p1[2 * i + 1]);
    float rs = ((s8[0] + s8[1]) + (s8[2] + s8[3])) +
               ((s8[4] + s8[5]) + (s8[6] + s8[7]));
    {
      float xa = rs, xb = rs;
      asm("" : "+v"(xb));
      PLSWAP(xa, xb);
      rs = xa + xb;
    }
    l += rs;

    // ---- pack P -> B-frag words; cross-half exchange via permlane ----
    u32 w0[8], w1[8];
#pragma unroll
    for (int i = 0; i < 8; ++i) {
      w0[i] = cvtpk(p0[2 * i], p0[2 * i + 1]);
      w1[i] = cvtpk(p1[2 * i], p1[2 * i + 1]);
    }
    // swap(a=w[4sl+0], b=w[4sl+2]): a[32:63]<->b[0:31] per true ISA semantics
    // -> lanes<32 get {w0_self,w1_self,w0_hi1,w1_hi1}; lanes>=32 get
    //    {w2_hi0,w3_hi0,w2_self,w3_self} — exact mfma32 B-frag k-order.
#pragma unroll
    for (int sl = 0; sl < 2; ++sl) {
      PLSWAP(w0[4 * sl + 0], w0[4 * sl + 2]);
      PLSWAP(w0[4 * sl + 1], w0[4 * sl + 3]);
      PLSWAP(w1[4 * sl + 0], w1[4 * sl + 2]);
      PLSWAP(w1[4 * sl + 1], w1[4 * sl + 3]);
    }

    // ---- PV: 8 MFMAs ----
    __builtin_amdgcn_s_setprio(1);
#pragma unroll
    for (int sl = 0; sl < 2; ++sl) {
      union { u32 uw[4]; bh8 h; } pa0, pa1;
#pragma unroll
      for (int j = 0; j < 4; ++j) { pa0.uw[j] = w0[4 * sl + j]; pa1.uw[j] = w1[4 * sl + j]; }
      O0 = MFMA32(vf[0][sl][0], pa0.h, O0);
      O1 = MFMA32(vf[0][sl][1], pa0.h, O1);
      O0 = MFMA32(vf[1][sl][0], pa1.h, O0);
      O1 = MFMA32(vf[1][sl][1], pa1.h, O1);
    }
    __builtin_amdgcn_s_setprio(0);
  }

  // epilogue: O^T[d][q]/l -> attnw[(b*S + q0+q)][h*64 + d]
  const float inv = 1.0f / l;
  unsigned short* orow =
      attnw + (size_t)(bz * SS + q0 + q) * DD + by * HDIM;
#pragma unroll
  for (int rq = 0; rq < 4; ++rq) {
    const int db0 = 8 * rq + 4 * hi;
    uint2 v0, v1;
    v0.x = cvtpk(O0[4 * rq + 0] * inv, O0[4 * rq + 1] * inv);
    v0.y = cvtpk(O0[4 * rq + 2] * inv, O0[4 * rq + 3] * inv);
    v1.x = cvtpk(O1[4 * rq + 0] * inv, O1[4 * rq + 1] * inv);
    v1.y = cvtpk(O1[4 * rq + 2] * inv, O1[4 * rq + 3] * inv);
    *(uint2*)(orow + db0) = v0;
    *(uint2*)(orow + 32 + db0) = v1;
  }
}

// ---------- launch ----------
extern "C" void kernel_launch(void* const* d_in, const int* in_sizes, int n_in,
                              void* d_out, int out_size, void* d_ws,
                              size_t ws_size, hipStream_t stream) {
  const float* x  = (const float*)d_in[0];
  const float* Wq = (const float*)d_in[1];
  const float* bq = (const float*)d_in[2];
  const float* Wk = (const float*)d_in[3];
  const float* bk = (const float*)d_in[4];
  const float* Wv = (const float*)d_in[5];
  const float* bv = (const float*)d_in[6];
  const float* Wo = (const float*)d_in[7];
  const float* bo = (const float*)d_in[8];
  float* out = (float*)d_out;

  unsigned short* ws = (unsigned short*)d_ws;
  unsigned short* xb    = ws;                    // 4M  [T, D]
  unsigned short* Wqb   = ws + 4194304;          // 1M x4 (Wq,Wk,Wv,Wo contiguous)
  unsigned short* Qw    = ws + 8388608;          // 4M  [B,H,S,Hd] (pre-scaled)
  unsigned short* Kw    = ws + 12582912;         // 4M  [B,H,S,Hd]
  unsigned short* Vtw   = ws + 16777216;         // 4M  [B,H,Hd,S]
  unsigned short* attnw = ws + 20971520;         // 4M  [T, D]

  cvt_f32_bf16<<<(TT * DD / 8 + 255) / 256, 256, 0, stream>>>(x, xb, TT * DD / 8);
  cvt_w4<<<dim3(DD * DD / 8 / 256, 4), 256, 0, stream>>>(Wq, Wk, Wv, Wo, Wqb);

  gemm128<0><<<dim3(TT / 128, 3072 / 128), 256, 0, stream>>>(
      xb, Wqb, bq, bk, bv, Qw, Kw, Vtw, nullptr);

  attn4<<<dim3(512), 256, 0, stream>>>(Qw, Kw, Vtw, attnw);

  gemm128<1><<<dim3(TT / 128, DD / 128), 256, 0, stream>>>(
      attnw, Wqb + 3 * 1048576, bo, nullptr, nullptr, nullptr, nullptr, nullptr, out);
}